// Round 9
// baseline (102.442 us; speedup 1.0000x reference)
//
#include <hip/hip_runtime.h>
#include <hip/hip_bf16.h>

// Fused GATConv + proj + LayerNorm + ReLU. N=50000, E=800000, F_IN=128, H=4, C=16, D=128.
//   k_prep    : zero deg_sh + pack W/proj_w into bf16 hi/lo MFMA fragments; fold bias
//   k_xw_rank : FUSED: (a) xp = x@W split-bf16 MFMA + logits, (b) rank capture via
//               XCD-local sharded histogram: shard = TRUE XCD id (s_getreg HW_REG_XCC_ID),
//               workgroup-scope atomics -> execute in XCD-local L2, not at the fabric.
//   k_scan1   : per-node 8-shard sum -> per-shard base (in place) + block-exclusive scan
//   k_scan23  : each block prefix-scans partials in LDS, adds base -> global row_ptr
//   k_fill    : atomic-free scatter: colsrc[row_ptr[d] + shard_base[d] + rank] = src
//   k_agg2    : segment softmax + aggregation; wave covers 4 edges per vmem instruction
//   k_proj    : aggr(bf16) @ proj_w^T + pb2, LayerNorm, ReLU (32 MFMA)

#define LEAKY(x) ((x) > 0.f ? (x) : 0.2f * (x))
#define NSH 8

typedef __attribute__((ext_vector_type(8))) short bf16x8;
typedef __attribute__((ext_vector_type(4))) float f32x4;

static __device__ __forceinline__ unsigned short f2bf_rne(float f) {
    unsigned u = __float_as_uint(f);
    return (unsigned short)((u + 0x7FFFu + ((u >> 16) & 1u)) >> 16);
}
static __device__ __forceinline__ float bf2f(unsigned short h) {
    return __uint_as_float(((unsigned)h) << 16);
}
// True XCD id of the CU this wave runs on (gfx940+/gfx950; HW-verified on MI355X).
static __device__ __forceinline__ int xcd_id() {
    int x;
    asm volatile("s_getreg_b32 %0, hwreg(HW_REG_XCC_ID)" : "=s"(x));
    return x & (NSH - 1);
}

// idx [0,8192): W frags; [8192,16384): proj_w frags; [16384,16512): pb2;
// [16512, 16512+8N): deg_sh = 0
__global__ __launch_bounds__(256) void k_prep(
    const float* __restrict__ W, const float* __restrict__ bias,
    const float* __restrict__ proj_w, const float* __restrict__ proj_b,
    unsigned short* __restrict__ Whf, unsigned short* __restrict__ Wlf,
    unsigned short* __restrict__ Phf, unsigned short* __restrict__ Plf,
    float* __restrict__ pb2, int* __restrict__ deg_sh, int n_nodes)
{
    int idx = blockIdx.x * 256 + threadIdx.x;
    if (idx < 8192) {
        int j = idx & 7, lane = (idx >> 3) & 63, ts = idx >> 9;
        int t = ts >> 2, s = ts & 3;
        int k = s * 32 + ((lane >> 4) << 3) + j;
        int n = t * 16 + (lane & 15);
        float w = W[k * 64 + n];
        unsigned short wh = f2bf_rne(w);
        Whf[idx] = wh;
        Wlf[idx] = f2bf_rne(w - bf2f(wh));
    } else if (idx < 16384) {
        int i2 = idx - 8192;
        int j = i2 & 7, lane = (i2 >> 3) & 63, ts = i2 >> 9;
        int t = ts >> 1, s = ts & 1;
        int k = s * 32 + ((lane >> 4) << 3) + j;   // 0..63
        int d = t * 16 + (lane & 15);              // 0..127
        float w = proj_w[d * 64 + k];
        unsigned short wh = f2bf_rne(w);
        Phf[i2] = wh;
        Plf[i2] = f2bf_rne(w - bf2f(wh));
    } else if (idx < 16384 + 128) {
        int d = idx - 16384;
        float s = proj_b[d];
        for (int j = 0; j < 64; j++) s += bias[j] * proj_w[d * 64 + j];
        pb2[d] = s;
    } else if (idx >= 16512 && idx < 16512 + NSH * n_nodes) {
        deg_sh[idx - 16512] = 0;
    }
}

// FUSED xw + rank. Every P-th block (bid % P == P-1) does one 64-node xw tile;
// the rest each rank a 1024-edge chunk (4 edges/thread, independent atomics).
// Rank atomics: workgroup scope + true-XCD shard -> executed in XCD-local L2.
__global__ __launch_bounds__(256) void k_xw_rank(
    const float* __restrict__ x,
    const unsigned short* __restrict__ Whf, const unsigned short* __restrict__ Wlf,
    const float* __restrict__ att_src, const float* __restrict__ att_dst,
    unsigned short* __restrict__ xp, float* __restrict__ a_src, float* __restrict__ a_dst,
    int n_nodes,
    const int* __restrict__ dst, int* __restrict__ deg_sh, int* __restrict__ erank, int E,
    int P)
{
    int bid = blockIdx.x;
    int t = threadIdx.x;
    if (bid % P != P - 1) {
        // ---- rank path: 4 edges per thread, XCD-local L2 atomics ----
        int shard = xcd_id();
        int* degS = deg_sh + (size_t)shard * n_nodes;
        int rb = bid - bid / P;
        int e0 = rb * 1024 + t;
        bool v0 = e0 < E, v1 = e0 + 256 < E, v2 = e0 + 512 < E, v3 = e0 + 768 < E;
        int d0 = 0, d1 = 0, d2 = 0, d3 = 0;
        if (v0) d0 = dst[e0];
        if (v1) d1 = dst[e0 + 256];
        if (v2) d2 = dst[e0 + 512];
        if (v3) d3 = dst[e0 + 768];
        int r0 = 0, r1 = 0, r2 = 0, r3 = 0;
        if (v0) r0 = __hip_atomic_fetch_add(&degS[d0], 1, __ATOMIC_RELAXED, __HIP_MEMORY_SCOPE_WORKGROUP);
        if (v1) r1 = __hip_atomic_fetch_add(&degS[d1], 1, __ATOMIC_RELAXED, __HIP_MEMORY_SCOPE_WORKGROUP);
        if (v2) r2 = __hip_atomic_fetch_add(&degS[d2], 1, __ATOMIC_RELAXED, __HIP_MEMORY_SCOPE_WORKGROUP);
        if (v3) r3 = __hip_atomic_fetch_add(&degS[d3], 1, __ATOMIC_RELAXED, __HIP_MEMORY_SCOPE_WORKGROUP);
        if (v0) erank[e0]       = (r0 << 3) | shard;
        if (v1) erank[e0 + 256] = (r1 << 3) | shard;
        if (v2) erank[e0 + 512] = (r2 << 3) | shard;
        if (v3) erank[e0 + 768] = (r3 << 3) | shard;
        return;
    }
    // ---- xw path ----
    int xb = bid / P;
    int w = t >> 6, lane = t & 63;
    int mbase = xb * 64 + w * 16;
    int mrow = lane & 15, kg = lane >> 4;
    int node = mbase + mrow;
    if (node >= n_nodes) node = n_nodes - 1;   // clamp; fake rows never stored

    bf16x8 ah[4], al[4];
#pragma unroll
    for (int s = 0; s < 4; s++) {
        const float* px = x + (size_t)node * 128 + s * 32 + kg * 8;
        float4 v0 = *(const float4*)px;
        float4 v1 = *(const float4*)(px + 4);
        float f[8] = {v0.x, v0.y, v0.z, v0.w, v1.x, v1.y, v1.z, v1.w};
#pragma unroll
        for (int j = 0; j < 8; j++) {
            unsigned short h = f2bf_rne(f[j]);
            ah[s][j] = (short)h;
            al[s][j] = (short)f2bf_rne(f[j] - bf2f(h));
        }
    }

    f32x4 acc[4];
#pragma unroll
    for (int tt = 0; tt < 4; tt++) acc[tt] = (f32x4){0.f, 0.f, 0.f, 0.f};

#pragma unroll
    for (int tt = 0; tt < 4; tt++) {
#pragma unroll
        for (int s = 0; s < 4; s++) {
            size_t fi = (size_t)(((tt * 4 + s) * 64 + lane) * 8);
            bf16x8 bh = *(const bf16x8*)(Whf + fi);
            bf16x8 bl = *(const bf16x8*)(Wlf + fi);
            acc[tt] = __builtin_amdgcn_mfma_f32_16x16x32_bf16(ah[s], bh, acc[tt], 0, 0, 0);
            acc[tt] = __builtin_amdgcn_mfma_f32_16x16x32_bf16(ah[s], bl, acc[tt], 0, 0, 0);
            acc[tt] = __builtin_amdgcn_mfma_f32_16x16x32_bf16(al[s], bh, acc[tt], 0, 0, 0);
        }
    }

    // D layout: col=lane&15, row=(lane>>4)*4+reg. Tile tt == head tt.
#pragma unroll
    for (int tt = 0; tt < 4; tt++) {
        float asv = att_src[tt * 16 + mrow];
        float adv = att_dst[tt * 16 + mrow];
#pragma unroll
        for (int r = 0; r < 4; r++) {
            float v = acc[tt][r];
            int n2 = mbase + kg * 4 + r;
            bool ok = (n2 < n_nodes);
            if (ok) xp[(size_t)n2 * 64 + tt * 16 + mrow] = f2bf_rne(v);
            float ts = v * asv;
            float td = v * adv;
#pragma unroll
            for (int off = 8; off; off >>= 1) {
                ts += __shfl_xor(ts, off);
                td += __shfl_xor(td, off);
            }
            if (mrow == 0 && ok) {
                a_src[n2 * 4 + tt] = ts;
                a_dst[n2 * 4 + tt] = td;
            }
        }
    }
}

// Per node g: running-prefix the 8 shard counts in place (deg_sh[s][g] becomes the
// base offset of shard s within node g); total -> block-exclusive scan in row_ptr.
__global__ __launch_bounds__(256) void k_scan1(int* __restrict__ deg_sh, int* __restrict__ row_ptr,
                                               int* __restrict__ partial, int n)
{
    __shared__ int sh[256];
    int t = threadIdx.x, g = blockIdx.x * 256 + t;
    int v = 0;
    if (g < n) {
#pragma unroll
        for (int s = 0; s < NSH; s++) {
            int c = deg_sh[s * n + g];
            deg_sh[s * n + g] = v;
            v += c;
        }
    }
    sh[t] = v; __syncthreads();
    for (int off = 1; off < 256; off <<= 1) {
        int u = (t >= off) ? sh[t - off] : 0;
        __syncthreads();
        sh[t] += u;
        __syncthreads();
    }
    if (g < n) row_ptr[g] = sh[t] - v;          // block-exclusive
    if (t == 255) partial[blockIdx.x] = sh[255]; // block total
}

// Each block prefix-scans all block totals in LDS (nblk <= 256), adds its base.
__global__ __launch_bounds__(256) void k_scan23(int* __restrict__ row_ptr, const int* __restrict__ partial,
                                                int n, int E_total, int nblk)
{
    __shared__ int sh[256];
    int t = threadIdx.x, g = blockIdx.x * 256 + t;
    sh[t] = (t < nblk) ? partial[t] : 0;
    __syncthreads();
    for (int off = 1; off < 256; off <<= 1) {
        int u = (t >= off) ? sh[t - off] : 0;
        __syncthreads();
        sh[t] += u;
        __syncthreads();
    }
    int base = (blockIdx.x > 0) ? sh[blockIdx.x - 1] : 0;  // exclusive prefix of this block
    if (g < n) row_ptr[g] += base;
    if (g == 0) row_ptr[n] = E_total;
}

// Atomic-free CSR fill: slot = row_ptr[d] + shard_base[d] + local rank.
__global__ __launch_bounds__(256) void k_fill(const int* __restrict__ src, const int* __restrict__ dst,
                                              const int* __restrict__ erank, const int* __restrict__ row_ptr,
                                              const int* __restrict__ deg_sh,
                                              int* __restrict__ colsrc, int E, int n_nodes)
{
    int e = blockIdx.x * 256 + threadIdx.x;
    if (e < E) {
        int d = dst[e];
        int er = erank[e];
        int shard = er & (NSH - 1), r = er >> 3;
        colsrc[row_ptr[d] + deg_sh[(size_t)shard * n_nodes + d] + r] = src[e];
    }
}

// Gather kernel: one node per wave. Wave covers 4 edges per vmem instruction:
// lane = (edge-parity = lane>>4) x (channel-group = lane&15, 4 bf16 channels each).
__global__ __launch_bounds__(256, 8) void k_agg2(
    const unsigned short* __restrict__ xp, const float* __restrict__ a_src, const float* __restrict__ a_dst,
    const int* __restrict__ row_ptr, const int* __restrict__ colsrc,
    unsigned short* __restrict__ aggr, int n_nodes)
{
    __shared__ int   sstage[4][64];       // 1 KB
    __shared__ float alpha_s[4][64][4];   // 4 KB
    int t = threadIdx.x, w = t >> 6, lane = t & 63;
    int cgrp = lane & 15;     // channels 4*cgrp .. 4*cgrp+3
    int epar = lane >> 4;     // edge parity 0..3
    int h = cgrp >> 2;        // head of my channels
    int n = blockIdx.x * 4 + w;
    if (n >= n_nodes) return;
    int rp0 = row_ptr[n], rp1 = row_ptr[n + 1];
    float4 ad4 = *(const float4*)&a_dst[(size_t)n * 4];
    float ax = 0.f, ay = 0.f, az = 0.f, aw = 0.f, den = 0.f;
    for (int base = rp0; base < rp1; base += 64) {
        int cnt = rp1 - base; if (cnt > 64) cnt = 64;
        int s = 0;
        float4 p = make_float4(0.f, 0.f, 0.f, 0.f);
        if (lane < cnt) {
            s = colsrc[base + lane];
            float4 as4 = *(const float4*)&a_src[(size_t)s * 4];
            p.x = __expf(LEAKY(as4.x + ad4.x));
            p.y = __expf(LEAKY(as4.y + ad4.y));
            p.z = __expf(LEAKY(as4.z + ad4.z));
            p.w = __expf(LEAKY(as4.w + ad4.w));
        }
        sstage[w][lane] = s;
        *(float4*)&alpha_s[w][lane][0] = p;
        // same-wave LDS write->read is in-order; no barrier needed.
        // padded entries (j >= cnt) have alpha 0 / s 0 -> contribute nothing.
        int iters = (cnt + 3) >> 2;
        for (int it = 0; it < iters; ++it) {
            int j = (it << 2) + epar;
            int sj = sstage[w][j];
            float aj = alpha_s[w][j][h];
            ushort4 v = *(const ushort4*)(xp + (size_t)((unsigned)sj * 64u + (cgrp << 2)));
            den += aj;
            ax += aj * bf2f(v.x);
            ay += aj * bf2f(v.y);
            az += aj * bf2f(v.z);
            aw += aj * bf2f(v.w);
        }
    }
    // combine the 4 edge-parity groups (lane^16 flips parity bit0, lane^32 bit1)
    ax += __shfl_xor(ax, 16); ax += __shfl_xor(ax, 32);
    ay += __shfl_xor(ay, 16); ay += __shfl_xor(ay, 32);
    az += __shfl_xor(az, 16); az += __shfl_xor(az, 32);
    aw += __shfl_xor(aw, 16); aw += __shfl_xor(aw, 32);
    den += __shfl_xor(den, 16); den += __shfl_xor(den, 32);
    if (lane < 16) {
        float inv = 1.f / (den + 1e-16f);
        ushort4 o;
        o.x = f2bf_rne(ax * inv);
        o.y = f2bf_rne(ay * inv);
        o.z = f2bf_rne(az * inv);
        o.w = f2bf_rne(aw * inv);
        *(ushort4*)(aggr + (size_t)n * 64 + (cgrp << 2)) = o;
    }
}

// proj + LN + ReLU: aggr is bf16 -> A fragments load directly (lo-term exactly 0),
// weights stay hi/lo split -> 2 MFMA per (tt,s) = 32 total, zero conversion VALU.
__global__ __launch_bounds__(256, 4) void k_proj(
    const unsigned short* __restrict__ aggr,
    const unsigned short* __restrict__ Phf, const unsigned short* __restrict__ Plf,
    const float* __restrict__ pb2, const float* __restrict__ gamma, const float* __restrict__ beta,
    float* __restrict__ out, int n_nodes)
{
    __shared__ float pb_s[128], g_s[128], b_s[128];
    int t = threadIdx.x;
    if (t < 128) { pb_s[t] = pb2[t]; g_s[t] = gamma[t]; b_s[t] = beta[t]; }
    __syncthreads();
    int w = t >> 6, lane = t & 63;
    int mbase = blockIdx.x * 64 + w * 16;
    int mrow = lane & 15, kg = lane >> 4;
    int node = mbase + mrow;
    if (node >= n_nodes) node = n_nodes - 1;

    bf16x8 ah[2];
#pragma unroll
    for (int s = 0; s < 2; s++) {
        ah[s] = *(const bf16x8*)(aggr + (size_t)node * 64 + s * 32 + kg * 8);
    }

    f32x4 acc[8];
#pragma unroll
    for (int tt = 0; tt < 8; tt++) acc[tt] = (f32x4){0.f, 0.f, 0.f, 0.f};
#pragma unroll
    for (int tt = 0; tt < 8; tt++) {
#pragma unroll
        for (int s = 0; s < 2; s++) {
            size_t fi = (size_t)(((tt * 2 + s) * 64 + lane) * 8);
            bf16x8 bh = *(const bf16x8*)(Phf + fi);
            bf16x8 bl = *(const bf16x8*)(Plf + fi);
            acc[tt] = __builtin_amdgcn_mfma_f32_16x16x32_bf16(ah[s], bh, acc[tt], 0, 0, 0);
            acc[tt] = __builtin_amdgcn_mfma_f32_16x16x32_bf16(ah[s], bl, acc[tt], 0, 0, 0);
        }
    }

    // D layout: d = tt*16 + (lane&15), node_row = kg*4 + r
#pragma unroll
    for (int r = 0; r < 4; r++) {
        int nr = mbase + kg * 4 + r;
        float vv[8];
        float S = 0.f, Q = 0.f;
#pragma unroll
        for (int tt = 0; tt < 8; tt++) {
            float v = acc[tt][r] + pb_s[tt * 16 + mrow];
            vv[tt] = v;
            S += v;
            Q += v * v;
        }
#pragma unroll
        for (int off = 8; off; off >>= 1) {
            S += __shfl_xor(S, off);
            Q += __shfl_xor(Q, off);
        }
        float mu  = S * (1.f / 128.f);
        float var = Q * (1.f / 128.f) - mu * mu;
        float inv = rsqrtf(var + 1e-5f);
        if (nr < n_nodes) {
#pragma unroll
            for (int tt = 0; tt < 8; tt++) {
                int d = tt * 16 + mrow;
                float o = fmaxf((vv[tt] - mu) * inv * g_s[d] + b_s[d], 0.f);
                out[(size_t)nr * 128 + d] = o;
            }
        }
    }
}

extern "C" void kernel_launch(void* const* d_in, const int* in_sizes, int n_in,
                              void* d_out, int out_size, void* d_ws, size_t ws_size,
                              hipStream_t stream)
{
    const float* x       = (const float*)d_in[0];
    const int*   ei      = (const int*)  d_in[1];
    const float* W       = (const float*)d_in[2];
    const float* att_src = (const float*)d_in[3];
    const float* att_dst = (const float*)d_in[4];
    const float* bias    = (const float*)d_in[5];
    const float* proj_w  = (const float*)d_in[6];
    const float* proj_b  = (const float*)d_in[7];
    const float* gamma   = (const float*)d_in[8];
    const float* beta    = (const float*)d_in[9];

    int N = in_sizes[0] / 128;
    int E = in_sizes[1] / 2;
    const int* srcIdx = ei;
    const int* dstIdx = ei + E;

    char* ws = (char*)d_ws;
    unsigned short* xp   = (unsigned short*)ws; ws += (size_t)N * 64 * 2;
    unsigned short* aggr = (unsigned short*)ws; ws += (size_t)N * 64 * 2;
    float* a_src   = (float*)ws; ws += (size_t)N * 4 * 4;
    float* a_dst   = (float*)ws; ws += (size_t)N * 4 * 4;
    int*   deg_sh  = (int*)ws;   ws += (size_t)NSH * N * 4;
    int*   row_ptr = (int*)ws;   ws += (size_t)(N + 1) * 4;
    int*   partial = (int*)ws;   ws += 256 * 4;
    int*   colsrc  = (int*)ws;   ws += (size_t)E * 4;
    int*   erank   = (int*)ws;   ws += (size_t)E * 4;
    unsigned short* Whf = (unsigned short*)ws; ws += 8192 * 2;
    unsigned short* Wlf = (unsigned short*)ws; ws += 8192 * 2;
    unsigned short* Phf = (unsigned short*)ws; ws += 8192 * 2;
    unsigned short* Plf = (unsigned short*)ws; ws += 8192 * 2;
    float* pb2 = (float*)ws; ws += 128 * 4;

    int nbXw   = (N + 63) / 64;
    int nbRank = (E + 1023) / 1024;
    int nblk   = (N + 255) / 256;

    // interleave period: one xw block per (P-1) rank blocks
    int P = (nbRank + nbXw - 1) / nbXw + 1;
    int totalFused = nbXw * P;

    k_prep<<<(16512 + NSH * N + 255) / 256, 256, 0, stream>>>(W, bias, proj_w, proj_b,
                                                              Whf, Wlf, Phf, Plf, pb2, deg_sh, N);
    k_xw_rank<<<totalFused, 256, 0, stream>>>(x, Whf, Wlf, att_src, att_dst,
                                              xp, a_src, a_dst, N,
                                              dstIdx, deg_sh, erank, E, P);
    k_scan1<<<nblk, 256, 0, stream>>>(deg_sh, row_ptr, partial, N);
    k_scan23<<<nblk, 256, 0, stream>>>(row_ptr, partial, N, E, nblk);
    k_fill<<<(E + 255) / 256, 256, 0, stream>>>(srcIdx, dstIdx, erank, row_ptr, deg_sh, colsrc, E, N);
    k_agg2<<<(N + 3) / 4, 256, 0, stream>>>(xp, a_src, a_dst, row_ptr, colsrc, aggr, N);
    k_proj<<<(N + 63) / 64, 256, 0, stream>>>(aggr, Phf, Plf, pb2, gamma, beta, (float*)d_out, N);
}